// Round 13
// baseline (646.571 us; speedup 1.0000x reference)
//
#include <hip/hip_runtime.h>
#include <math.h>

// Problem constants
#define B_  16
#define LU_ 2048
#define LV_ 2048
#define D_  1024
#define NTC_ 8            // softmax stats granularity: LV/256
#define MB_ (1024ull * 1024ull)

typedef __attribute__((ext_vector_type(8))) short ush8;
typedef __attribute__((ext_vector_type(8))) _Float16 f16x8;
typedef __attribute__((ext_vector_type(4))) float f32x4;

__device__ __forceinline__ unsigned short f2h(float x) {
    _Float16 h = (_Float16)x;
    return __builtin_bit_cast(unsigned short, h);
}

__device__ __forceinline__ void gload_lds16(const void* g, void* l) {
    __builtin_amdgcn_global_load_lds(
        (const __attribute__((address_space(1))) void*)g,
        (__attribute__((address_space(3))) void*)l, 16, 0, 0);
}

__device__ __forceinline__ void raw_barrier() {
    asm volatile("" ::: "memory");
    __builtin_amdgcn_s_barrier();
    asm volatile("" ::: "memory");
}

// ---------------------------------------------------------------------------
// K0: per-batch valid length from mask, with byte-vs-int32 layout detection.
__global__ void lengths_kernel(const void* __restrict__ mask, int* __restrict__ lengths) {
    __shared__ int viol;
    __shared__ int cnt[B_];
    const int t = threadIdx.x;
    if (t == 0) viol = 0;
    if (t < B_) cnt[t] = 0;
    __syncthreads();
    const unsigned char* mb = (const unsigned char*)mask;
    int local = 0;
    for (int i = t; i < B_ * LV_ - 1; i += 256) {
        if (((i + 1) % LV_) != 0) {
            if (mb[i] != 0 && mb[i + 1] == 0) local++;
        }
    }
    if (local) atomicAdd(&viol, local);
    __syncthreads();
    const bool is_i32 = (viol > 0);
    const int b = t >> 4, s = t & 15;
    int c = 0;
    if (is_i32) {
        const int* mi = (const int*)mask;
        for (int v2 = s; v2 < LV_; v2 += 16) c += (mi[b * LV_ + v2] == 0) ? 1 : 0;
    } else {
        for (int v2 = s; v2 < LV_; v2 += 16) c += (mb[b * LV_ + v2] == 0) ? 1 : 0;
    }
    atomicAdd(&cnt[b], c);
    __syncthreads();
    if (t < B_) lengths[t] = cnt[t];
}

// ---------------------------------------------------------------------------
// K1: fp32 -> fp16 cast
__global__ __launch_bounds__(256) void cvt_kernel(
    const float* __restrict__ X, unsigned short* __restrict__ Y, long n8) {
    const long stride = (long)gridDim.x * 256;
    for (long i = (long)blockIdx.x * 256 + threadIdx.x; i < n8; i += stride) {
        float4 x0 = ((const float4*)X)[i * 2];
        float4 x1 = ((const float4*)X)[i * 2 + 1];
        float xv[8] = {x0.x, x0.y, x0.z, x0.w, x1.x, x1.y, x1.z, x1.w};
        ush8 h;
#pragma unroll
        for (int j = 0; j < 8; j++) h[j] = (short)f2h(xv[j]);
        ((ush8*)Y)[i] = h;
    }
}

// ===========================================================================
// 256x256-tile, 512-thread (8-wave 2Mx4N), BK=64, double-buffered LDS,
// counted-vmcnt pipeline (T3+T4): raw barriers, vmcnt(8) in steady state,
// STAGE(t+2) issued after the frag-consumption barrier. Proven chunk-XOR
// swizzle (pre-swizzled global source + swizzled ds_read, conflicts=0).
// LDS: sA[2][256*64] + sB[2][256*64] shorts = 128 KiB dynamic.
// ===========================================================================

// K2: Y = relu(X @ W^T + b), fp16. Grid (B*L/256, D/256).
__global__ __launch_bounds__(512, 2) void proj_kernel(
    const unsigned short* __restrict__ Xf, const unsigned short* __restrict__ Wf,
    const float* __restrict__ bias, const int* __restrict__ lengths, int is_v,
    unsigned short* __restrict__ Yf) {
    if (is_v) {
        const int bb = blockIdx.x >> 3;          // 8 row-tiles of 256 per batch
        const int lv0 = (blockIdx.x & 7) * 256;
        if (lv0 >= lengths[bb]) return;
    }
    extern __shared__ unsigned short lds[];
    unsigned short* sA = lds;            // [2][16384]
    unsigned short* sB = lds + 32768;
    const int t = threadIdx.x, lane = t & 63, w = t >> 6;
    const int wm = w >> 2, wn = w & 3;
    const int fr = lane & 15, fg = lane >> 4;
    const int row0 = blockIdx.x * 256, col0 = blockIdx.y * 256;

    size_t aog[4], bog[4];
    int dbs[4];
#pragma unroll
    for (int i = 0; i < 4; i++) {
        const int r = w * 32 + i * 8 + (lane >> 3);
        const int cg = (lane & 7) ^ (r & 7);
        aog[i] = (size_t)(row0 + r) * D_ + cg * 8;
        bog[i] = (size_t)(col0 + r) * D_ + cg * 8;
        dbs[i] = (w * 32 + i * 8) * 64;
    }
    int aoff[2][8], boff[2][4];
#pragma unroll
    for (int kk = 0; kk < 2; kk++) {
#pragma unroll
        for (int m = 0; m < 8; m++) {
            const int r = wm * 128 + m * 16 + fr;
            aoff[kk][m] = r * 64 + (((kk * 4 + fg) ^ (r & 7))) * 8;
        }
#pragma unroll
        for (int n = 0; n < 4; n++) {
            const int r = wn * 64 + n * 16 + fr;
            boff[kk][n] = r * 64 + (((kk * 4 + fg) ^ (r & 7))) * 8;
        }
    }

    const f32x4 fzero = {0.f, 0.f, 0.f, 0.f};
    f32x4 acc[8][4];
#pragma unroll
    for (int m = 0; m < 8; m++)
#pragma unroll
        for (int n = 0; n < 4; n++) acc[m][n] = fzero;

    const int NKT = D_ / 64;
    // prologue: stage tiles 0 and 1
#pragma unroll
    for (int i = 0; i < 4; i++) {
        gload_lds16(Xf + aog[i], &sA[dbs[i]]);
        gload_lds16(Wf + bog[i], &sB[dbs[i]]);
    }
#pragma unroll
    for (int i = 0; i < 4; i++) {
        gload_lds16(Xf + aog[i] + 64, &sA[16384 + dbs[i]]);
        gload_lds16(Wf + bog[i] + 64, &sB[16384 + dbs[i]]);
    }

#pragma unroll 1
    for (int tk = 0; tk < NKT; ++tk) {
        const int d = (tk & 1) * 16384;
        if (tk < NKT - 1) asm volatile("s_waitcnt vmcnt(8)" ::: "memory");
        else              asm volatile("s_waitcnt vmcnt(0)" ::: "memory");
        raw_barrier();
#pragma unroll
        for (int kk = 0; kk < 2; kk++) {
            f16x8 av[8], bv[4];
#pragma unroll
            for (int m = 0; m < 8; m++) av[m] = *(const f16x8*)&sA[d + aoff[kk][m]];
#pragma unroll
            for (int n = 0; n < 4; n++) bv[n] = *(const f16x8*)&sB[d + boff[kk][n]];
            __builtin_amdgcn_s_setprio(1);
#pragma unroll
            for (int m = 0; m < 8; m++)
#pragma unroll
                for (int n = 0; n < 4; n++)
                    acc[m][n] = __builtin_amdgcn_mfma_f32_16x16x32_f16(av[m], bv[n], acc[m][n], 0, 0, 0);
            __builtin_amdgcn_s_setprio(0);
        }
        raw_barrier();
        if (tk + 2 < NKT) {
            const size_t ka = (size_t)(tk + 2) * 64;
#pragma unroll
            for (int i = 0; i < 4; i++) {
                gload_lds16(Xf + aog[i] + ka, &sA[d + dbs[i]]);
                gload_lds16(Wf + bog[i] + ka, &sB[d + dbs[i]]);
            }
        }
    }

#pragma unroll
    for (int n = 0; n < 4; n++) {
        const int col = col0 + wn * 64 + n * 16 + fr;
        const float bv = bias[col];
#pragma unroll
        for (int m = 0; m < 8; m++) {
#pragma unroll
            for (int j = 0; j < 4; j++) {
                const int row = row0 + wm * 128 + m * 16 + fg * 4 + j;
                const float y = fmaxf(acc[m][n][j] + bv, 0.f);
                Yf[(size_t)row * D_ + col] = f2h(y);
            }
        }
    }
}

// ---------------------------------------------------------------------------
// K3: v fp32 -> vT fp16 [B][D][LV] AND vraw fp16 [B][LV][D]; ceil128 skip.
__global__ __launch_bounds__(256) void transpose_v_kernel(
    const float* __restrict__ V, const int* __restrict__ lengths,
    unsigned short* __restrict__ VT, unsigned short* __restrict__ Vraw) {
    __shared__ unsigned short s[64 * 72];
    const int b = blockIdx.z;
    const int v0 = blockIdx.x * 64, d0 = blockIdx.y * 64;
    if (v0 >= ((lengths[b] + 127) & ~127)) return;
    const int t = threadIdx.x;
    {
        const int r = t >> 2, q = (t & 3) * 16;
        const float* src = V + ((size_t)b * LV_ + v0 + r) * D_ + d0 + q;
        unsigned short hb[16];
#pragma unroll
        for (int i = 0; i < 4; i++) {
            float4 x = ((const float4*)src)[i];
            hb[i * 4 + 0] = f2h(x.x);
            hb[i * 4 + 1] = f2h(x.y);
            hb[i * 4 + 2] = f2h(x.z);
            hb[i * 4 + 3] = f2h(x.w);
        }
#pragma unroll
        for (int j = 0; j < 16; j++) s[r * 72 + q + j] = hb[j];
        unsigned short* rdst = Vraw + ((size_t)b * LV_ + v0 + r) * D_ + d0 + q;
        ((ush8*)rdst)[0] = *(ush8*)&hb[0];
        ((ush8*)rdst)[1] = *(ush8*)&hb[8];
    }
    __syncthreads();
    {
        const int d = t >> 2, vq = (t & 3) * 16;
        ush8 t0, t1;
#pragma unroll
        for (int j = 0; j < 8; j++) t0[j] = (short)s[(vq + j) * 72 + d];
#pragma unroll
        for (int j = 0; j < 8; j++) t1[j] = (short)s[(vq + 8 + j) * 72 + d];
        unsigned short* dst = VT + ((size_t)b * D_ + d0 + d) * LV_ + v0 + vq;
        ((ush8*)dst)[0] = t0;
        ((ush8*)dst)[1] = t1;
    }
}

// ---------------------------------------------------------------------------
// K4: logits, 256x256 tile, pipelined core; stats at 256-col granularity.
// Grid (LU/256, LV/256, B).
__global__ __launch_bounds__(512, 2) void attn_logits_kernel(
    const unsigned short* __restrict__ Uf, const unsigned short* __restrict__ Vf,
    const int* __restrict__ lengths,
    unsigned short* __restrict__ Pp, float* __restrict__ m_used,
    float* __restrict__ Z_used) {
    extern __shared__ unsigned short lds[];
    unsigned short* sA = lds;
    unsigned short* sB = lds + 32768;
    const int b = blockIdx.z, ut = blockIdx.x, vty = blockIdx.y;
    const int t = threadIdx.x, lane = t & 63, w = t >> 6;
    const int wm = w >> 2, wn = w & 3;
    const int fr = lane & 15, fg = lane >> 4;
    const int length = lengths[b];
    const int row0 = ut * 256, col0 = vty * 256;

    if (col0 >= length) {   // fully-masked 256-group: degenerate stats only
        if (t < 256) {
            const size_t row = (size_t)b * LU_ + row0 + t;
            m_used[row * NTC_ + vty] = -__builtin_inff();
            Z_used[row * NTC_ + vty] = 0.f;
        }
        return;
    }

    size_t aog[4], bog[4];
    int dbs[4];
#pragma unroll
    for (int i = 0; i < 4; i++) {
        const int r = w * 32 + i * 8 + (lane >> 3);
        const int cg = (lane & 7) ^ (r & 7);
        aog[i] = ((size_t)b * LU_ + row0 + r) * D_ + cg * 8;
        bog[i] = ((size_t)b * LV_ + col0 + r) * D_ + cg * 8;
        dbs[i] = (w * 32 + i * 8) * 64;
    }
    int aoff[2][8], boff[2][4];
#pragma unroll
    for (int kk = 0; kk < 2; kk++) {
#pragma unroll
        for (int m = 0; m < 8; m++) {
            const int r = wm * 128 + m * 16 + fr;
            aoff[kk][m] = r * 64 + (((kk * 4 + fg) ^ (r & 7))) * 8;
        }
#pragma unroll
        for (int n = 0; n < 4; n++) {
            const int r = wn * 64 + n * 16 + fr;
            boff[kk][n] = r * 64 + (((kk * 4 + fg) ^ (r & 7))) * 8;
        }
    }

    const f32x4 fzero = {0.f, 0.f, 0.f, 0.f};
    f32x4 acc[8][4];
#pragma unroll
    for (int m = 0; m < 8; m++)
#pragma unroll
        for (int n = 0; n < 4; n++) acc[m][n] = fzero;

    const int NKT = D_ / 64;
#pragma unroll
    for (int i = 0; i < 4; i++) {
        gload_lds16(Uf + aog[i], &sA[dbs[i]]);
        gload_lds16(Vf + bog[i], &sB[dbs[i]]);
    }
#pragma unroll
    for (int i = 0; i < 4; i++) {
        gload_lds16(Uf + aog[i] + 64, &sA[16384 + dbs[i]]);
        gload_lds16(Vf + bog[i] + 64, &sB[16384 + dbs[i]]);
    }

#pragma unroll 1
    for (int tk = 0; tk < NKT; ++tk) {
        const int d = (tk & 1) * 16384;
        if (tk < NKT - 1) asm volatile("s_waitcnt vmcnt(8)" ::: "memory");
        else              asm volatile("s_waitcnt vmcnt(0)" ::: "memory");
        raw_barrier();
#pragma unroll
        for (int kk = 0; kk < 2; kk++) {
            f16x8 av[8], bv[4];
#pragma unroll
            for (int m = 0; m < 8; m++) av[m] = *(const f16x8*)&sA[d + aoff[kk][m]];
#pragma unroll
            for (int n = 0; n < 4; n++) bv[n] = *(const f16x8*)&sB[d + boff[kk][n]];
            __builtin_amdgcn_s_setprio(1);
#pragma unroll
            for (int m = 0; m < 8; m++)
#pragma unroll
                for (int n = 0; n < 4; n++)
                    acc[m][n] = __builtin_amdgcn_mfma_f32_16x16x32_f16(av[m], bv[n], acc[m][n], 0, 0, 0);
            __builtin_amdgcn_s_setprio(0);
        }
        raw_barrier();
        if (tk + 2 < NKT) {
            const size_t ka = (size_t)(tk + 2) * 64;
#pragma unroll
            for (int i = 0; i < 4; i++) {
                gload_lds16(Uf + aog[i] + ka, &sA[d + dbs[i]]);
                gload_lds16(Vf + bog[i] + ka, &sB[d + dbs[i]]);
            }
        }
    }

    // ---- stats over 256 rows x 256 cols (cross-wave via LDS) ----
    __syncthreads();
    float* sMax = (float*)lds;           // [256][4]
    float* sSum = sMax + 1024;           // [256][4]
#pragma unroll
    for (int m = 0; m < 8; m++) {
        float mt[4] = {-__builtin_inff(), -__builtin_inff(), -__builtin_inff(), -__builtin_inff()};
#pragma unroll
        for (int n = 0; n < 4; n++) {
            const int col = col0 + wn * 64 + n * 16 + fr;
            if (col < length) {
#pragma unroll
                for (int j = 0; j < 4; j++) mt[j] = fmaxf(mt[j], acc[m][n][j]);
            }
        }
#pragma unroll
        for (int dd = 1; dd < 16; dd <<= 1) {
#pragma unroll
            for (int j = 0; j < 4; j++) mt[j] = fmaxf(mt[j], __shfl_xor(mt[j], dd));
        }
        if (fr == 0) {
#pragma unroll
            for (int j = 0; j < 4; j++)
                sMax[(wm * 128 + m * 16 + fg * 4 + j) * 4 + wn] = mt[j];
        }
    }
    __syncthreads();
#pragma unroll
    for (int m = 0; m < 8; m++) {
        float mrow[4], rs[4] = {0.f, 0.f, 0.f, 0.f};
#pragma unroll
        for (int j = 0; j < 4; j++) {
            const int rl = wm * 128 + m * 16 + fg * 4 + j;
            mrow[j] = fmaxf(fmaxf(sMax[rl * 4 + 0], sMax[rl * 4 + 1]),
                            fmaxf(sMax[rl * 4 + 2], sMax[rl * 4 + 3]));
        }
#pragma unroll
        for (int n = 0; n < 4; n++) {
            const int col = col0 + wn * 64 + n * 16 + fr;
            const bool valid = (col < length);
#pragma unroll
            for (int j = 0; j < 4; j++) {
                const float p = valid ? __expf(acc[m][n][j] - mrow[j]) : 0.f;
                rs[j] += p;
                const size_t row = (size_t)b * LU_ + row0 + wm * 128 + m * 16 + fg * 4 + j;
                Pp[row * LV_ + col] = f2h(p);
            }
        }
#pragma unroll
        for (int dd = 1; dd < 16; dd <<= 1) {
#pragma unroll
            for (int j = 0; j < 4; j++) rs[j] += __shfl_xor(rs[j], dd);
        }
        if (fr == 0) {
#pragma unroll
            for (int j = 0; j < 4; j++)
                sSum[(wm * 128 + m * 16 + fg * 4 + j) * 4 + wn] = rs[j];
        }
    }
    __syncthreads();
    if (t < 256) {
        const float m_t = fmaxf(fmaxf(sMax[t * 4 + 0], sMax[t * 4 + 1]),
                                fmaxf(sMax[t * 4 + 2], sMax[t * 4 + 3]));
        const float z = sSum[t * 4 + 0] + sSum[t * 4 + 1] + sSum[t * 4 + 2] + sSum[t * 4 + 3];
        const size_t row = (size_t)b * LU_ + row0 + t;
        m_used[row * NTC_ + vty] = m_t;
        Z_used[row * NTC_ + vty] = z;
    }
}

// ---------------------------------------------------------------------------
// K6: out = sum (Sc * P') @ V. 256x256 tile, pipelined core; fused combine.
// Grid (LU/256, D/256, B). K capped at ceil128(length).
__global__ __launch_bounds__(512, 2) void pv_gemm_kernel(
    const unsigned short* __restrict__ Pp, const unsigned short* __restrict__ VT,
    const float* __restrict__ m_used, const float* __restrict__ Z_used,
    const int* __restrict__ lengths, float* __restrict__ Out) {
    extern __shared__ unsigned short lds[];
    unsigned short* sA = lds;
    unsigned short* sB = lds + 32768;
    float* sSc = (float*)(lds + 65536);  // [8][256] = 8KB
    const int b = blockIdx.z, bm = blockIdx.x, bn = blockIdx.y;
    const int t = threadIdx.x, lane = t & 63, w = t >> 6;
    const int wm = w >> 2, wn = w & 3;
    const int fr = lane & 15, fg = lane >> 4;
    const int length = lengths[b];
    const int nkt = ((length + 127) >> 7) * 2;   // K-tiles of 64, >= 16

    // fused stats combine -> sSc[vt256][row-local]
    if (t < 256) {
        const size_t row = (size_t)b * LU_ + bm * 256 + t;
        float mv[NTC_];
        float m = -__builtin_inff();
#pragma unroll
        for (int i = 0; i < NTC_; i++) {
            mv[i] = m_used[row * NTC_ + i];
            m = fmaxf(m, mv[i]);
        }
        float z = 0.f;
        float ev[NTC_];
#pragma unroll
        for (int i = 0; i < NTC_; i++) {
            ev[i] = __expf(mv[i] - m);
            z += Z_used[row * NTC_ + i] * ev[i];
        }
        const float inv = 1.f / z;
#pragma unroll
        for (int i = 0; i < NTC_; i++) sSc[i * 256 + t] = ev[i] * inv;
    }
    __syncthreads();

    size_t aog[4], bog[4];
    int dbs[4];
#pragma unroll
    for (int i = 0; i < 4; i++) {
        const int r = w * 32 + i * 8 + (lane >> 3);
        const int cg = (lane & 7) ^ (r & 7);
        aog[i] = ((size_t)b * LU_ + bm * 256 + r) * LV_ + cg * 8;
        bog[i] = ((size_t)b * D_ + bn * 256 + r) * LV_ + cg * 8;
        dbs[i] = (w * 32 + i * 8) * 64;
    }
    int aoff[2][8], boff[2][4];
#pragma unroll
    for (int kk = 0; kk < 2; kk++) {
#pragma unroll
        for (int m = 0; m < 8; m++) {
            const int r = wm * 128 + m * 16 + fr;
            aoff[kk][m] = r * 64 + (((kk * 4 + fg) ^ (r & 7))) * 8;
        }
#pragma unroll
        for (int n = 0; n < 4; n++) {
            const int r = wn * 64 + n * 16 + fr;
            boff[kk][n] = r * 64 + (((kk * 4 + fg) ^ (r & 7))) * 8;
        }
    }

    const f32x4 fzero = {0.f, 0.f, 0.f, 0.f};
    f32x4 acc[8][4];
#pragma unroll
    for (int m = 0; m < 8; m++)
#pragma unroll
        for (int n = 0; n < 4; n++) acc[m][n] = fzero;

#pragma unroll
    for (int i = 0; i < 4; i++) {
        gload_lds16(Pp + aog[i], &sA[dbs[i]]);
        gload_lds16(VT + bog[i], &sB[dbs[i]]);
    }
#pragma unroll
    for (int i = 0; i < 4; i++) {
        gload_lds16(Pp + aog[i] + 64, &sA[16384 + dbs[i]]);
        gload_lds16(VT + bog[i] + 64, &sB[16384 + dbs[i]]);
    }

#pragma unroll 1
    for (int tk = 0; tk < nkt; ++tk) {
        const int d = (tk & 1) * 16384;
        const int vt256 = tk >> 2;
        _Float16 scv[8];
#pragma unroll
        for (int m = 0; m < 8; m++)
            scv[m] = (_Float16)sSc[vt256 * 256 + wm * 128 + m * 16 + fr];
        if (tk < nkt - 1) asm volatile("s_waitcnt vmcnt(8)" ::: "memory");
        else              asm volatile("s_waitcnt vmcnt(0)" ::: "memory");
        raw_barrier();
#pragma unroll
        for (int kk = 0; kk < 2; kk++) {
            f16x8 av[8], bv[4];
#pragma unroll
            for (int m = 0; m < 8; m++)
                av[m] = (*(const f16x8*)&sA[d + aoff[kk][m]]) * scv[m];
#pragma unroll
            for (int n = 0; n < 4; n++) bv[n] = *(const f16x8*)&sB[d + boff[kk][n]];
            __builtin_amdgcn_s_setprio(1);
#pragma unroll
            for (int m = 0; m < 8; m++)
#pragma unroll
                for (int n = 0; n < 4; n++)
                    acc[m][n] = __builtin_amdgcn_mfma_f32_16x16x32_f16(av[m], bv[n], acc[m][n], 0, 0, 0);
            __builtin_amdgcn_s_setprio(0);
        }
        raw_barrier();
        if (tk + 2 < nkt) {
            const size_t ka = (size_t)(tk + 2) * 64;
#pragma unroll
            for (int i = 0; i < 4; i++) {
                gload_lds16(Pp + aog[i] + ka, &sA[d + dbs[i]]);
                gload_lds16(VT + bog[i] + ka, &sB[d + dbs[i]]);
            }
        }
    }

    float* Ob = Out + (size_t)b * LU_ * D_;
#pragma unroll
    for (int m = 0; m < 8; m++) {
        const int rbase = bm * 256 + wm * 128 + m * 16 + fg * 4;
#pragma unroll
        for (int n = 0; n < 4; n++) {
            const int col = bn * 256 + wn * 64 + n * 16 + fr;
#pragma unroll
            for (int j = 0; j < 4; j++)
                Ob[(size_t)(rbase + j) * D_ + col] = acc[m][n][j];
        }
    }
}

// ---------------------------------------------------------------------------
extern "C" void kernel_launch(void* const* d_in, const int* in_sizes, int n_in,
                              void* d_out, int out_size, void* d_ws, size_t ws_size,
                              hipStream_t stream) {
    (void)in_sizes; (void)n_in; (void)out_size; (void)ws_size;
    const float* u    = (const float*)d_in[0];
    const float* v    = (const float*)d_in[1];
    const void*  vm   = d_in[2];
    const float* W    = (const float*)d_in[3];
    const float* bias = (const float*)d_in[4];
    float* out = (float*)d_out;
    char* ws = (char*)d_ws;

    unsigned short* Pp    = (unsigned short*)(ws + 0 * MB_);     // 128MB fp16
    unsigned short* vT    = (unsigned short*)(ws + 128 * MB_);   // 64MB fp16
    unsigned short* u_f   = (unsigned short*)(ws + 192 * MB_);   // 64MB
    unsigned short* v_f   = (unsigned short*)(ws + 256 * MB_);   // 64MB
    unsigned short* vraw  = (unsigned short*)(ws + 320 * MB_);   // 64MB
    unsigned short* xs_u  = (unsigned short*)(ws + 384 * MB_);   // 64MB
    unsigned short* W_f   = (unsigned short*)(ws + 448 * MB_);   // 2MB
    int*   lengths = (int*)(ws + 450 * MB_);
    float* m_used  = (float*)(ws + 451 * MB_);                   // 1MB used
    float* Z_used  = (float*)(ws + 453 * MB_);

    const long nW8 = (long)D_ * D_ / 8;
    const long nX8 = (long)B_ * LU_ * D_ / 8;
    const size_t LDSB  = 131072;
    const size_t LDSBP = 139264;   // + 8KB sSc

    lengths_kernel<<<1, 256, 0, stream>>>(vm, lengths);
    cvt_kernel<<<512, 256, 0, stream>>>(W, W_f, nW8);
    cvt_kernel<<<4096, 256, 0, stream>>>(u, xs_u, nX8);
    proj_kernel<<<dim3(B_ * LU_ / 256, D_ / 256), 512, LDSB, stream>>>(
        xs_u, W_f, bias, lengths, 0, u_f);
    transpose_v_kernel<<<dim3(LV_ / 64, D_ / 64, B_), 256, 0, stream>>>(v, lengths, vT, vraw);
    proj_kernel<<<dim3(B_ * LV_ / 256, D_ / 256), 512, LDSB, stream>>>(
        vraw, W_f, bias, lengths, 1, v_f);
    attn_logits_kernel<<<dim3(LU_ / 256, LV_ / 256, B_), 512, LDSB, stream>>>(
        u_f, v_f, lengths, Pp, m_used, Z_used);
    pv_gemm_kernel<<<dim3(LU_ / 256, D_ / 256, B_), 512, LDSBP, stream>>>(
        Pp, vT, m_used, Z_used, lengths, out);
}

// Round 14
// 574.917 us; speedup vs baseline: 1.1246x; 1.1246x over previous
//
#include <hip/hip_runtime.h>
#include <math.h>

// Problem constants
#define B_  16
#define LU_ 2048
#define LV_ 2048
#define D_  1024
#define NT_ (LV_ / 128)   // 16 v-tiles of 128
#define MB_ (1024ull * 1024ull)

typedef __attribute__((ext_vector_type(8))) short ush8;        // 8 x 16-bit storage
typedef __attribute__((ext_vector_type(8))) _Float16 f16x8;    // MFMA A/B fragment
typedef __attribute__((ext_vector_type(4))) float f32x4;

__device__ __forceinline__ unsigned short f2h(float x) {
    _Float16 h = (_Float16)x;                 // v_cvt_f16_f32, RNE
    return __builtin_bit_cast(unsigned short, h);
}

__device__ __forceinline__ void gload_lds16(const void* g, void* l) {
    __builtin_amdgcn_global_load_lds(
        (const __attribute__((address_space(1))) void*)g,
        (__attribute__((address_space(3))) void*)l, 16, 0, 0);
}

// ---------------------------------------------------------------------------
// K0: per-batch valid length from mask, with byte-vs-int32 layout detection.
__global__ void lengths_kernel(const void* __restrict__ mask, int* __restrict__ lengths) {
    __shared__ int viol;
    __shared__ int cnt[B_];
    const int t = threadIdx.x;
    if (t == 0) viol = 0;
    if (t < B_) cnt[t] = 0;
    __syncthreads();
    const unsigned char* mb = (const unsigned char*)mask;
    int local = 0;
    for (int i = t; i < B_ * LV_ - 1; i += 256) {
        if (((i + 1) % LV_) != 0) {
            if (mb[i] != 0 && mb[i + 1] == 0) local++;
        }
    }
    if (local) atomicAdd(&viol, local);
    __syncthreads();
    const bool is_i32 = (viol > 0);
    const int b = t >> 4, s = t & 15;
    int c = 0;
    if (is_i32) {
        const int* mi = (const int*)mask;
        for (int v2 = s; v2 < LV_; v2 += 16) c += (mi[b * LV_ + v2] == 0) ? 1 : 0;
    } else {
        for (int v2 = s; v2 < LV_; v2 += 16) c += (mb[b * LV_ + v2] == 0) ? 1 : 0;
    }
    atomicAdd(&cnt[b], c);
    __syncthreads();
    if (t < B_) lengths[t] = cnt[t];
}

// ---------------------------------------------------------------------------
// K1: fp32 -> fp16 cast (elementwise, 8 elems/thread, grid-stride)
__global__ __launch_bounds__(256) void cvt_kernel(
    const float* __restrict__ X, unsigned short* __restrict__ Y, long n8) {
    const long stride = (long)gridDim.x * 256;
    for (long i = (long)blockIdx.x * 256 + threadIdx.x; i < n8; i += stride) {
        float4 x0 = ((const float4*)X)[i * 2];
        float4 x1 = ((const float4*)X)[i * 2 + 1];
        float xv[8] = {x0.x, x0.y, x0.z, x0.w, x1.x, x1.y, x1.z, x1.w};
        ush8 h;
#pragma unroll
        for (int j = 0; j < 8; j++) h[j] = (short)f2h(xv[j]);
        ((ush8*)Y)[i] = h;
    }
}

// ---------------------------------------------------------------------------
// K2: Y = relu(X @ W^T + b), all fp16, single-term MFMA GEMM.
// 128x128 tile, BK=64 (PV-proven staging/swizzle), 4 waves of 32 rows x 128 cols.
// is_v != 0: skip row-blocks that are fully masked (lv0 >= lengths[b]).
__global__ __launch_bounds__(256, 2) void proj_kernel(
    const unsigned short* __restrict__ Xf, const unsigned short* __restrict__ Wf,
    const float* __restrict__ bias, const int* __restrict__ lengths, int is_v,
    unsigned short* __restrict__ Yf) {
    if (is_v) {
        const int bb = blockIdx.x >> 4;          // 16 blocks of 128 rows per batch
        const int lv0 = (blockIdx.x & 15) * 128;
        if (lv0 >= lengths[bb]) return;          // fully-masked row block
    }
    __shared__ alignas(16) unsigned short sA[128 * 64], sB[128 * 64];
    const int t = threadIdx.x, lane = t & 63, w = t >> 6;
    const int fr = lane & 15, fg = lane >> 4;
    const int row0 = blockIdx.x * 128, col0 = blockIdx.y * 128;

    // staging (PV-proven): wave w rows [w*32,+32), issue i rows [w*32+i*8,+8)
    size_t aog[4], bog[4];
    int dbs[4];
#pragma unroll
    for (int i = 0; i < 4; i++) {
        const int r = w * 32 + i * 8 + (lane >> 3);
        const int cg = (lane & 7) ^ (r & 7);
        aog[i] = (size_t)(row0 + r) * D_ + cg * 8;
        bog[i] = (size_t)(col0 + r) * D_ + cg * 8;
        dbs[i] = (w * 32 + i * 8) * 64;
    }
    // fragment read offsets (PV-proven swizzle family)
    int aoff[2][2], boff[2][8];
#pragma unroll
    for (int kk = 0; kk < 2; kk++) {
#pragma unroll
        for (int m = 0; m < 2; m++) {
            const int r = w * 32 + m * 16 + fr;
            aoff[kk][m] = r * 64 + (((kk * 4 + fg) ^ (r & 7))) * 8;
        }
#pragma unroll
        for (int n = 0; n < 8; n++) {
            const int r = n * 16 + fr;
            boff[kk][n] = r * 64 + (((kk * 4 + fg) ^ (r & 7))) * 8;
        }
    }

    const f32x4 fzero = {0.f, 0.f, 0.f, 0.f};
    f32x4 acc[2][8];
#pragma unroll
    for (int m = 0; m < 2; m++)
#pragma unroll
        for (int n = 0; n < 8; n++) acc[m][n] = fzero;

#pragma unroll 1
    for (int k0 = 0; k0 < D_; k0 += 64) {
        __syncthreads();
#pragma unroll
        for (int i = 0; i < 4; i++) {
            gload_lds16(Xf + aog[i] + k0, &sA[dbs[i]]);
            gload_lds16(Wf + bog[i] + k0, &sB[dbs[i]]);
        }
        __syncthreads();
#pragma unroll
        for (int kk = 0; kk < 2; kk++) {
            const f16x8 a0 = *(const f16x8*)&sA[aoff[kk][0]];
            const f16x8 a1 = *(const f16x8*)&sA[aoff[kk][1]];
#pragma unroll
            for (int n = 0; n < 8; n++) {
                const f16x8 bv = *(const f16x8*)&sB[boff[kk][n]];
                acc[0][n] = __builtin_amdgcn_mfma_f32_16x16x32_f16(a0, bv, acc[0][n], 0, 0, 0);
                acc[1][n] = __builtin_amdgcn_mfma_f32_16x16x32_f16(a1, bv, acc[1][n], 0, 0, 0);
            }
        }
    }

#pragma unroll
    for (int m = 0; m < 2; m++)
#pragma unroll
        for (int n = 0; n < 8; n++) {
            const int col = col0 + n * 16 + fr;
            const float bv = bias[col];
#pragma unroll
            for (int j = 0; j < 4; j++) {
                const int row = row0 + w * 32 + m * 16 + fg * 4 + j;
                const float y = fmaxf(acc[m][n][j] + bv, 0.f);
                Yf[(size_t)row * D_ + col] = f2h(y);
            }
        }
}

// ---------------------------------------------------------------------------
// K3: v fp32 [B][LV][D] -> vT fp16 [B][D][LV]  AND  vraw fp16 [B][LV][D]
// Skips blocks with v0 >= ceil128(length): those rows are only ever multiplied
// by exactly-zero P' (PV) or masked (logits). ceil128 (not length) because PV
// reads full 128-K tiles and proj-v reads full 128-row blocks — rows below
// ceil128 MUST be real data (uninit ws could be Inf -> 0*Inf=NaN otherwise).
__global__ __launch_bounds__(256) void transpose_v_kernel(
    const float* __restrict__ V, const int* __restrict__ lengths,
    unsigned short* __restrict__ VT, unsigned short* __restrict__ Vraw) {
    __shared__ unsigned short s[64 * 72];
    const int b = blockIdx.z;
    const int v0 = blockIdx.x * 64, d0 = blockIdx.y * 64;
    if (v0 >= ((lengths[b] + 127) & ~127)) return;
    const int t = threadIdx.x;
    {
        const int r = t >> 2, q = (t & 3) * 16;
        const float* src = V + ((size_t)b * LV_ + v0 + r) * D_ + d0 + q;
        unsigned short hb[16];
#pragma unroll
        for (int i = 0; i < 4; i++) {
            float4 x = ((const float4*)src)[i];
            hb[i * 4 + 0] = f2h(x.x);
            hb[i * 4 + 1] = f2h(x.y);
            hb[i * 4 + 2] = f2h(x.z);
            hb[i * 4 + 3] = f2h(x.w);
        }
#pragma unroll
        for (int j = 0; j < 16; j++) s[r * 72 + q + j] = hb[j];
        unsigned short* rdst = Vraw + ((size_t)b * LV_ + v0 + r) * D_ + d0 + q;
        ((ush8*)rdst)[0] = *(ush8*)&hb[0];
        ((ush8*)rdst)[1] = *(ush8*)&hb[8];
    }
    __syncthreads();
    {
        const int d = t >> 2, vq = (t & 3) * 16;
        ush8 t0, t1;
#pragma unroll
        for (int j = 0; j < 8; j++) t0[j] = (short)s[(vq + j) * 72 + d];
#pragma unroll
        for (int j = 0; j < 8; j++) t1[j] = (short)s[(vq + 8 + j) * 72 + d];
        unsigned short* dst = VT + ((size_t)b * D_ + d0 + d) * LV_ + v0 + vq;
        ((ush8*)dst)[0] = t0;
        ((ush8*)dst)[1] = t1;
    }
}

// ---------------------------------------------------------------------------
// K4: logits tile kernel. Grid (LU/128, NT, B) natural order (balanced across
// XCDs — R10 lesson: XCD-chunking + length-dependent work = imbalance).
// One 128x128 S-tile per WG, BK=64, per-tile softmax stats, P'=exp(S-m_t) fp16.
__global__ __launch_bounds__(256, 2) void attn_logits_kernel(
    const unsigned short* __restrict__ Uf, const unsigned short* __restrict__ Vf,
    const int* __restrict__ lengths,
    unsigned short* __restrict__ Pp, float* __restrict__ m_used,
    float* __restrict__ Z_used) {
    __shared__ alignas(16) unsigned short sU[128 * 64], sV[128 * 64];
    const int b = blockIdx.z, ut = blockIdx.x, vt = blockIdx.y;
    const int t = threadIdx.x, lane = t & 63, w = t >> 6;
    const int fr = lane & 15, fg = lane >> 4;
    const int length = lengths[b];
    const int row0 = ut * 128, col0 = vt * 128;

    if (col0 >= length) {   // fully-masked tile: degenerate stats only
        if (t < 128) {
            const size_t row = (size_t)b * LU_ + row0 + t;
            m_used[row * NT_ + vt] = -__builtin_inff();
            Z_used[row * NT_ + vt] = 0.f;
        }
        return;
    }

    size_t aog[4], bog[4];
    int dbs[4];
#pragma unroll
    for (int i = 0; i < 4; i++) {
        const int r = w * 32 + i * 8 + (lane >> 3);
        const int cg = (lane & 7) ^ (r & 7);
        aog[i] = ((size_t)b * LU_ + row0 + r) * D_ + cg * 8;
        bog[i] = ((size_t)b * LV_ + col0 + r) * D_ + cg * 8;
        dbs[i] = (w * 32 + i * 8) * 64;
    }
    int aoff[2][2], boff[2][8];
#pragma unroll
    for (int kk = 0; kk < 2; kk++) {
#pragma unroll
        for (int m = 0; m < 2; m++) {
            const int r = w * 32 + m * 16 + fr;
            aoff[kk][m] = r * 64 + (((kk * 4 + fg) ^ (r & 7))) * 8;
        }
#pragma unroll
        for (int n = 0; n < 8; n++) {
            const int r = n * 16 + fr;
            boff[kk][n] = r * 64 + (((kk * 4 + fg) ^ (r & 7))) * 8;
        }
    }

    const f32x4 fzero = {0.f, 0.f, 0.f, 0.f};
    f32x4 acc[2][8];
#pragma unroll
    for (int m = 0; m < 2; m++)
#pragma unroll
        for (int n = 0; n < 8; n++) acc[m][n] = fzero;

#pragma unroll 1
    for (int k0 = 0; k0 < D_; k0 += 64) {
        __syncthreads();
#pragma unroll
        for (int i = 0; i < 4; i++) {
            gload_lds16(Uf + aog[i] + k0, &sU[dbs[i]]);
            gload_lds16(Vf + bog[i] + k0, &sV[dbs[i]]);
        }
        __syncthreads();
#pragma unroll
        for (int kk = 0; kk < 2; kk++) {
            const f16x8 a0 = *(const f16x8*)&sU[aoff[kk][0]];
            const f16x8 a1 = *(const f16x8*)&sU[aoff[kk][1]];
#pragma unroll
            for (int n = 0; n < 8; n++) {
                const f16x8 bv = *(const f16x8*)&sV[boff[kk][n]];
                acc[0][n] = __builtin_amdgcn_mfma_f32_16x16x32_f16(a0, bv, acc[0][n], 0, 0, 0);
                acc[1][n] = __builtin_amdgcn_mfma_f32_16x16x32_f16(a1, bv, acc[1][n], 0, 0, 0);
            }
        }
    }

    // per-tile stats: rows are wave-local (wave = 32 rows x 128 cols)
#pragma unroll
    for (int m = 0; m < 2; m++) {
        float mt[4] = {-__builtin_inff(), -__builtin_inff(), -__builtin_inff(), -__builtin_inff()};
#pragma unroll
        for (int n = 0; n < 8; n++) {
            const int col = col0 + n * 16 + fr;
            if (col < length) {
#pragma unroll
                for (int j = 0; j < 4; j++) mt[j] = fmaxf(mt[j], acc[m][n][j]);
            }
        }
#pragma unroll
        for (int d = 1; d < 16; d <<= 1) {
#pragma unroll
            for (int j = 0; j < 4; j++) mt[j] = fmaxf(mt[j], __shfl_xor(mt[j], d));
        }
        float rs[4] = {0.f, 0.f, 0.f, 0.f};
#pragma unroll
        for (int n = 0; n < 8; n++) {
            const int col = col0 + n * 16 + fr;
            const bool valid = (col < length);
#pragma unroll
            for (int j = 0; j < 4; j++) {
                const float p = valid ? __expf(acc[m][n][j] - mt[j]) : 0.f;
                rs[j] += p;
                const size_t row = (size_t)b * LU_ + row0 + w * 32 + m * 16 + fg * 4 + j;
                Pp[row * LV_ + col] = f2h(p);
            }
        }
#pragma unroll
        for (int d = 1; d < 16; d <<= 1) {
#pragma unroll
            for (int j = 0; j < 4; j++) rs[j] += __shfl_xor(rs[j], d);
        }
        if (fr == 0) {
#pragma unroll
            for (int j = 0; j < 4; j++) {
                const size_t row = (size_t)b * LU_ + row0 + w * 32 + m * 16 + fg * 4 + j;
                m_used[row * NT_ + vt] = mt[j];
                Z_used[row * NT_ + vt] = rs[j];
            }
        }
    }
}

// ---------------------------------------------------------------------------
// K6: out = sum_vt (Sc(row,vt)*P'_vt) @ V_vt. Grid (LU/128, D/128, B) natural
// order (balanced). 128x128 tile, BK=64, 4 waves 2x2 of 64x64.
// Stats combine FUSED into the preload: each block recomputes its 128 rows'
// Sc = exp(m_t - m_fin)/Z from (m_used, Z_used) — identical serial fp32 math
// to the old stats kernel -> bit-identical. sSc transposed [NT][128]
// (conflict-free, R10-verified). Scale applied to the A-fragment.
__global__ __launch_bounds__(256, 4) void pv_gemm_kernel(
    const unsigned short* __restrict__ Pp, const unsigned short* __restrict__ VT,
    const float* __restrict__ m_used, const float* __restrict__ Z_used,
    const int* __restrict__ lengths, float* __restrict__ Out) {
    __shared__ alignas(16) unsigned short sA[128 * 64], sB[128 * 64];
    __shared__ float sSc[NT_ * 128];   // transposed: [vt][row]
    const int b = blockIdx.z, bm = blockIdx.x, bn = blockIdx.y;
    const int t = threadIdx.x, lane = t & 63, w = t >> 6;
    const int wr = (w >> 1) * 64, wc = (w & 1) * 64;
    const int fr = lane & 15, fg = lane >> 4;
    const int length = lengths[b];
    const int ntv = (length + 127) >> 7;   // valid v-tiles (block-uniform)

    // fused stats combine + transposed Sc preload (one row per thread t<128)
    if (t < 128) {
        const size_t row = (size_t)b * LU_ + bm * 128 + t;
        float mv[NT_];
        float m = -__builtin_inff();
#pragma unroll
        for (int i = 0; i < NT_; i++) {
            mv[i] = m_used[row * NT_ + i];
            m = fmaxf(m, mv[i]);
        }
        float ev[NT_];
        float z = 0.f;
#pragma unroll
        for (int i = 0; i < NT_; i++) {
            ev[i] = __expf(mv[i] - m);
            z += Z_used[row * NT_ + i] * ev[i];
        }
        const float inv = 1.f / z;
#pragma unroll
        for (int i = 0; i < NT_; i++) sSc[i * 128 + t] = ev[i] * inv;
    }
    __syncthreads();   // sSc read cross-thread below

    // staging: wave w rows [w*32, +32), issue i in {0..3} rows [w*32+i*8, +8)
    size_t aog[4], bog[4];
    int dbs[4];
#pragma unroll
    for (int i = 0; i < 4; i++) {
        const int r = w * 32 + i * 8 + (lane >> 3);
        const int cg = (lane & 7) ^ (r & 7);
        aog[i] = ((size_t)b * LU_ + bm * 128 + r) * LV_ + cg * 8;
        bog[i] = ((size_t)b * D_ + bn * 128 + r) * LV_ + cg * 8;
        dbs[i] = (w * 32 + i * 8) * 64;
    }
    int aoff[2][4], boff[2][4];
#pragma unroll
    for (int kk = 0; kk < 2; kk++) {
#pragma unroll
        for (int m = 0; m < 4; m++) {
            const int r = wr + m * 16 + fr;
            aoff[kk][m] = r * 64 + (((kk * 4 + fg) ^ (r & 7))) * 8;
        }
#pragma unroll
        for (int n = 0; n < 4; n++) {
            const int r = wc + n * 16 + fr;
            boff[kk][n] = r * 64 + (((kk * 4 + fg) ^ (r & 7))) * 8;
        }
    }

    const f32x4 fzero = {0.f, 0.f, 0.f, 0.f};
    f32x4 acc[4][4];
#pragma unroll
    for (int m = 0; m < 4; m++)
#pragma unroll
        for (int n = 0; n < 4; n++) acc[m][n] = fzero;

#pragma unroll 1
    for (int vt = 0; vt < ntv; ++vt) {
        // per-row scale, transposed read: 16 consecutive floats, broadcast over fg
        f16x8 scv[4];
#pragma unroll
        for (int m = 0; m < 4; m++) {
            const _Float16 sh = (_Float16)sSc[vt * 128 + wr + m * 16 + fr];
#pragma unroll
            for (int j = 0; j < 8; j++) scv[m][j] = sh;
        }

#pragma unroll 1
        for (int kb = 0; kb < 2; ++kb) {
            const int k0 = vt * 128 + kb * 64;
            __syncthreads();
#pragma unroll
            for (int i = 0; i < 4; i++) {
                gload_lds16(Pp + aog[i] + k0, &sA[dbs[i]]);
                gload_lds16(VT + bog[i] + k0, &sB[dbs[i]]);
            }
            __syncthreads();
#pragma unroll
            for (int kk = 0; kk < 2; kk++) {
                f16x8 af[4];
#pragma unroll
                for (int m = 0; m < 4; m++)
                    af[m] = (*(const f16x8*)&sA[aoff[kk][m]]) * scv[m];
#pragma unroll
                for (int n = 0; n < 4; n++) {
                    const f16x8 bv = *(const f16x8*)&sB[boff[kk][n]];
#pragma unroll
                    for (int m = 0; m < 4; m++)
                        acc[m][n] = __builtin_amdgcn_mfma_f32_16x16x32_f16(af[m], bv, acc[m][n], 0, 0, 0);
                }
            }
        }
    }

    float* Ob = Out + (size_t)b * LU_ * D_;
#pragma unroll
    for (int m = 0; m < 4; m++) {
        const int rbase = bm * 128 + wr + m * 16 + fg * 4;
#pragma unroll
        for (int n = 0; n < 4; n++) {
            const int col = bn * 128 + wc + n * 16 + fr;
#pragma unroll
            for (int j = 0; j < 4; j++)
                Ob[(size_t)(rbase + j) * D_ + col] = acc[m][n][j];
        }
    }
}

// ---------------------------------------------------------------------------
extern "C" void kernel_launch(void* const* d_in, const int* in_sizes, int n_in,
                              void* d_out, int out_size, void* d_ws, size_t ws_size,
                              hipStream_t stream) {
    (void)in_sizes; (void)n_in; (void)out_size; (void)ws_size;
    const float* u    = (const float*)d_in[0];
    const float* v    = (const float*)d_in[1];
    const void*  vm   = d_in[2];
    const float* W    = (const float*)d_in[3];
    const float* bias = (const float*)d_in[4];
    float* out = (float*)d_out;
    char* ws = (char*)d_ws;

    // ws layout (~455 MB)
    unsigned short* Pp    = (unsigned short*)(ws + 0 * MB_);     // 128MB fp16
    unsigned short* vT    = (unsigned short*)(ws + 128 * MB_);   // 64MB fp16
    unsigned short* u_f   = (unsigned short*)(ws + 192 * MB_);   // 64MB u_ fp16
    unsigned short* v_f   = (unsigned short*)(ws + 256 * MB_);   // 64MB v_ fp16
    unsigned short* vraw  = (unsigned short*)(ws + 320 * MB_);   // 64MB raw v fp16
    unsigned short* xs_u  = (unsigned short*)(ws + 384 * MB_);   // 64MB raw u fp16
    unsigned short* W_f   = (unsigned short*)(ws + 448 * MB_);   // 2MB
    int*   lengths = (int*)(ws + 450 * MB_);
    float* m_used  = (float*)(ws + 451 * MB_);                   // 2MB
    float* Z_used  = (float*)(ws + 453 * MB_);                   // 2MB

    const long nW8 = (long)D_ * D_ / 8;
    const long nX8 = (long)B_ * LU_ * D_ / 8;

    lengths_kernel<<<1, 256, 0, stream>>>(vm, lengths);
    cvt_kernel<<<512, 256, 0, stream>>>(W, W_f, nW8);
    cvt_kernel<<<4096, 256, 0, stream>>>(u, xs_u, nX8);
    proj_kernel<<<dim3(B_ * LU_ / 128, D_ / 128), 256, 0, stream>>>(
        xs_u, W_f, bias, lengths, 0, u_f);
    transpose_v_kernel<<<dim3(LV_ / 64, D_ / 64, B_), 256, 0, stream>>>(v, lengths, vT, vraw);
    proj_kernel<<<dim3(B_ * LV_ / 128, D_ / 128), 256, 0, stream>>>(
        vraw, W_f, bias, lengths, 1, v_f);
    attn_logits_kernel<<<dim3(LU_ / 128, NT_, B_), 256, 0, stream>>>(
        u_f, v_f, lengths, Pp, m_used, Z_used);
    pv_gemm_kernel<<<dim3(LU_ / 128, D_ / 128, B_), 256, 0, stream>>>(
        Pp, vT, m_used, Z_used, lengths, out);
}